// Round 4
// baseline (236.470 us; speedup 1.0000x reference)
//
#include <hip/hip_runtime.h>
#include <hip/hip_bf16.h>

#define NB 64
#define S_ 1024
#define D_ 128

typedef __attribute__((ext_vector_type(8))) short bf16x8;
typedef __attribute__((ext_vector_type(4))) float f32x4;

__device__ __forceinline__ unsigned short f2bf(float f) {
  __hip_bfloat16 h = __float2bfloat16(f);
  return __builtin_bit_cast(unsigned short, h);
}

// ---- fused: per-batch partial stats (blocks 0..1023) + W pack (1024..3071) --
__global__ __launch_bounds__(256) void prep_kernel(
    const float* __restrict__ x, const float* __restrict__ W1,
    const float* __restrict__ W2, float2* __restrict__ part,
    unsigned short* __restrict__ W1b, unsigned short* __restrict__ W2b) {
  const int blk = blockIdx.x;
  if (blk < 1024) {
    const int b = blk >> 4, c = blk & 15, t = threadIdx.x;
    const float4* xb = (const float4*)(x + (size_t)b * (S_ * D_) + c * 8192);
    float s = 0.f, q = 0.f;
#pragma unroll
    for (int i = 0; i < 8; ++i) {
      float4 v = xb[i * 256 + t];
      s += v.x + v.y + v.z + v.w;
      q += v.x * v.x + v.y * v.y + v.z * v.z + v.w * v.w;
    }
#pragma unroll
    for (int o = 32; o > 0; o >>= 1) {
      s += __shfl_down(s, o, 64);
      q += __shfl_down(q, o, 64);
    }
    __shared__ float2 w4[4];
    const int wave = t >> 6, lane = t & 63;
    if (lane == 0) w4[wave] = make_float2(s, q);
    __syncthreads();
    if (t == 0) {
      float ss = 0.f, qq = 0.f;
#pragma unroll
      for (int i = 0; i < 4; ++i) { ss += w4[i].x; qq += w4[i].y; }
      part[blk] = make_float2(ss, qq);
    }
  } else {
    const int id = (blk - 1024) * 256 + threadIdx.x;  // 0 .. 524287
    const int perW = (S_ * S_) / 4;
    const float* src = (id < perW) ? W1 : W2;
    unsigned short* dst = (id < perW) ? W1b : W2b;
    const int i4 = (id < perW) ? id : id - perW;
    const int flat = i4 * 4;
    const int trow = flat >> 10;
    const int scol = flat & 1023;
    float4 v = ((const float4*)src)[i4];
    ushort4 o;
    o.x = f2bf((scol + 0 <= trow) ? v.x : 0.f);
    o.y = f2bf((scol + 1 <= trow) ? v.y : 0.f);
    o.z = f2bf((scol + 2 <= trow) ? v.z : 0.f);
    o.w = f2bf((scol + 3 <= trow) ? v.w : 0.f);
    *(ushort4*)(dst + flat) = o;
  }
}

// ------------- normalize + transpose: hT[b][d][s] (bf16) ---------------------
__global__ __launch_bounds__(256) void norm_t_kernel(const float* __restrict__ x,
                                                     const float* __restrict__ w,
                                                     const float* __restrict__ bb,
                                                     const float2* __restrict__ part,
                                                     unsigned short* __restrict__ hT) {
  __shared__ unsigned short lds[128 * 72];   // [d][s-tile 64 + 8 pad]
  const int blk = blockIdx.x;
  const int b = blk >> 4;
  const int s0 = (blk & 15) * 64;
  const int t = threadIdx.x;
  float sum = 0.f, sumq = 0.f;
#pragma unroll
  for (int i = 0; i < 16; ++i) {
    float2 p = part[b * 16 + i];
    sum += p.x; sumq += p.y;
  }
  const float inv = 1.0f / (S_ * D_);
  const float mu = sum * inv;
  const float rs = rsqrtf(sumq * inv - mu * mu + 1e-5f);

  const float4* xb = (const float4*)(x + ((size_t)b * S_ + s0) * D_);
  const float4* wb = (const float4*)(w + (size_t)s0 * D_);
  const float4* bv4 = (const float4*)(bb + (size_t)s0 * D_);
#pragma unroll
  for (int r = 0; r < 8; ++r) {
    const int f = r * 256 + t;
    const int srow = f >> 5;
    const int c4 = f & 31;
    float4 xv = xb[f];
    float4 wv = wb[f];
    float4 bvv = bv4[f];
    float h0 = (xv.x - mu) * rs * wv.x + bvv.x;
    float h1 = (xv.y - mu) * rs * wv.y + bvv.y;
    float h2 = (xv.z - mu) * rs * wv.z + bvv.z;
    float h3 = (xv.w - mu) * rs * wv.w + bvv.w;
    const int d0 = c4 * 4;
    lds[(d0 + 0) * 72 + srow] = f2bf(h0);
    lds[(d0 + 1) * 72 + srow] = f2bf(h1);
    lds[(d0 + 2) * 72 + srow] = f2bf(h2);
    lds[(d0 + 3) * 72 + srow] = f2bf(h3);
  }
  __syncthreads();
  unsigned short* outp = hT + (size_t)b * D_ * S_;
#pragma unroll
  for (int rr = 0; rr < 4; ++rr) {
    const int idx = rr * 256 + t;
    const int d = idx >> 3;
    const int ch = idx & 7;
    uint4 v = *(const uint4*)(lds + d * 72 + ch * 8);
    *(uint4*)(outp + d * S_ + s0 + ch * 8) = v;
  }
}

// ------------- causal batched GEMM, barrier-free K-loop ----------------------
// BM=64 (t), BN=128 (d); each wave owns 64m x 32n (wn = wave*32).
// Fragments load DIRECTLY global->VGPR (row = l16-based, k = quad*8): identical
// per-lane values to the old LDS path. 2-deep prefetch, unrolled x2, no
// __syncthreads in the K-loop => loads stay in flight across MFMAs
// (fine-grained vmcnt, AITER-style). LDS used only for the GEMM1 transpose
// epilogue. XCD-aware decode keeps a batch's Bt slice L2-resident; causal
// balance: mt = j<8 ? j : j^3 makes co-resident trip sums constant.
template <bool HSWISH>
__global__ __launch_bounds__(256, 4) void gemm_causal(
    const unsigned short* __restrict__ Wm, const unsigned short* __restrict__ Bt,
    unsigned short* __restrict__ Ut, const float* __restrict__ Xres,
    float* __restrict__ Out) {
  __shared__ __align__(16) unsigned short ldsT[128 * 72];

  const int t = threadIdx.x;
  const int wave = t >> 6, lane = t & 63;
  const int quad = lane >> 4, l16 = lane & 15;
  const int wn = wave * 32;

  const int bi = blockIdx.x;
  const int xcd = bi & 7;
  const int slot = bi >> 3;            // 0..127
  const int b = xcd * 8 + (slot & 7);
  const int j = slot >> 3;             // 0..15
  const int mt = (j < 8) ? j : (j ^ 3);
  const int row0 = mt * 64;

  const unsigned short* gA = Wm + ((size_t)row0 + l16) * S_ + quad * 8;
  const unsigned short* gB = Bt + ((size_t)b * D_ + wn + l16) * S_ + quad * 8;

  const int trips = 2 * (mt + 1);      // k-tiles of 32; always even, >= 2

  f32x4 acc[4][2] = {};
  bf16x8 A0[4], A1[4], B0[2], B1[2];

  // prologue: prefetch kt=0 (A0/B0) and kt=1 (A1/B1)
#pragma unroll
  for (int i = 0; i < 4; ++i) {
    A0[i] = *(const bf16x8*)(gA + i * 16 * S_);
    A1[i] = *(const bf16x8*)(gA + i * 16 * S_ + 32);
  }
#pragma unroll
  for (int jj = 0; jj < 2; ++jj) {
    B0[jj] = *(const bf16x8*)(gB + jj * 16 * S_);
    B1[jj] = *(const bf16x8*)(gB + jj * 16 * S_ + 32);
  }

  for (int kt = 0; kt < trips; kt += 2) {
    const int kpre0 = (kt + 2) * 32;
    const int kpre1 = (kt + 3) * 32;
    bf16x8 An[4], Bn[2], Am[4], Bm[2];
    if (kt + 2 < trips) {
#pragma unroll
      for (int i = 0; i < 4; ++i) {
        An[i] = *(const bf16x8*)(gA + i * 16 * S_ + kpre0);
        Am[i] = *(const bf16x8*)(gA + i * 16 * S_ + kpre1);
      }
#pragma unroll
      for (int jj = 0; jj < 2; ++jj) {
        Bn[jj] = *(const bf16x8*)(gB + jj * 16 * S_ + kpre0);
        Bm[jj] = *(const bf16x8*)(gB + jj * 16 * S_ + kpre1);
      }
    }
#pragma unroll
    for (int i = 0; i < 4; ++i)
#pragma unroll
      for (int jj = 0; jj < 2; ++jj)
        acc[i][jj] = __builtin_amdgcn_mfma_f32_16x16x32_bf16(A0[i], B0[jj],
                                                             acc[i][jj], 0, 0, 0);
#pragma unroll
    for (int i = 0; i < 4; ++i)
#pragma unroll
      for (int jj = 0; jj < 2; ++jj)
        acc[i][jj] = __builtin_amdgcn_mfma_f32_16x16x32_bf16(A1[i], B1[jj],
                                                             acc[i][jj], 0, 0, 0);
#pragma unroll
    for (int i = 0; i < 4; ++i) { A0[i] = An[i]; A1[i] = Am[i]; }
#pragma unroll
    for (int jj = 0; jj < 2; ++jj) { B0[jj] = Bn[jj]; B1[jj] = Bm[jj]; }
  }

  if (HSWISH) {
#pragma unroll
    for (int i = 0; i < 4; ++i)
#pragma unroll
      for (int jj = 0; jj < 2; ++jj) {
        ushort4 pk;
        float v0 = acc[i][jj][0], v1 = acc[i][jj][1], v2 = acc[i][jj][2], v3 = acc[i][jj][3];
        pk.x = f2bf(v0 * fminf(fmaxf(v0 + 3.f, 0.f), 6.f) * (1.f / 6.f));
        pk.y = f2bf(v1 * fminf(fmaxf(v1 + 3.f, 0.f), 6.f) * (1.f / 6.f));
        pk.z = f2bf(v2 * fminf(fmaxf(v2 + 3.f, 0.f), 6.f) * (1.f / 6.f));
        pk.w = f2bf(v3 * fminf(fmaxf(v3 + 3.f, 0.f), 6.f) * (1.f / 6.f));
        const int n = wn + jj * 16 + l16;           // d
        const int m0 = i * 16 + quad * 4;           // t within 64-tile
        *(ushort4*)(ldsT + n * 72 + m0) = pk;
      }
    __syncthreads();
    unsigned short* gU = Ut + (size_t)b * D_ * S_;
#pragma unroll
    for (int rr = 0; rr < 4; ++rr) {
      const int idx = rr * 256 + t;
      const int d = idx >> 3;
      const int ch = idx & 7;
      uint4 v = *(const uint4*)(ldsT + d * 72 + ch * 8);
      *(uint4*)(gU + d * S_ + row0 + ch * 8) = v;
    }
  } else {
    float* gO = Out + (size_t)b * S_ * D_;
    const float* gX = Xres + (size_t)b * S_ * D_;
#pragma unroll
    for (int i = 0; i < 4; ++i) {
      const int mrow0 = row0 + i * 16 + quad * 4;
#pragma unroll
      for (int jj = 0; jj < 2; ++jj) {
        const int col = wn + jj * 16 + l16;
#pragma unroll
        for (int r = 0; r < 4; ++r) {
          const int addr = (mrow0 + r) * D_ + col;
          gO[addr] = gX[addr] + acc[i][jj][r];
        }
      }
    }
  }
}

extern "C" void kernel_launch(void* const* d_in, const int* in_sizes, int n_in,
                              void* d_out, int out_size, void* d_ws, size_t ws_size,
                              hipStream_t stream) {
  const float* x = (const float*)d_in[0];
  const float* ln_w = (const float*)d_in[1];
  const float* ln_b = (const float*)d_in[2];
  const float* W1 = (const float*)d_in[3];
  const float* W2 = (const float*)d_in[4];
  float* out = (float*)d_out;

  char* ws = (char*)d_ws;
  float2* part = (float2*)ws;                                // 8 KiB
  unsigned short* W1b = (unsigned short*)(ws + 16384);       // 2 MiB
  unsigned short* W2b = W1b + (size_t)S_ * S_;               // 2 MiB
  unsigned short* hT = W2b + (size_t)S_ * S_;                // 16 MiB
  unsigned short* uT = hT + (size_t)NB * D_ * S_;            // 16 MiB

  prep_kernel<<<3072, 256, 0, stream>>>(x, W1, W2, part, W1b, W2b);
  norm_t_kernel<<<NB * 16, 256, 0, stream>>>(x, ln_w, ln_b, part, hT);
  gemm_causal<true><<<1024, 256, 0, stream>>>(W1b, hT, uT, nullptr, nullptr);
  gemm_causal<false><<<1024, 256, 0, stream>>>(W2b, uT, nullptr, x, out);
}

// Round 5
// 180.576 us; speedup vs baseline: 1.3095x; 1.3095x over previous
//
#include <hip/hip_runtime.h>
#include <hip/hip_bf16.h>

#define NB 64
#define S_ 1024
#define D_ 128

typedef __attribute__((ext_vector_type(8))) short bf16x8;
typedef __attribute__((ext_vector_type(4))) float f32x4;

// Fragment-tiled layout: operand matrices are stored as 16x32 panels of 1KB,
// element (r, k) of a panel at short-offset (((k>>3)&3)*16 + (r&15))*8 + (k&7)
// == lane*8 + j in MFMA A/B fragment order. A wave's fragment load is then
// base + lane*16B: one fully-coalesced 1KB global_load_dwordx4.

__device__ __forceinline__ unsigned short f2bf(float f) {
  __hip_bfloat16 h = __float2bfloat16(f);
  return __builtin_bit_cast(unsigned short, h);
}

// ---- fused: per-batch partial stats (blocks 0..1023) + W pack (1024..3071) --
// W1/W2 are tril-masked, bf16-cast, and written in fragment-tiled layout:
// panel P = t>>4 (64), chunk c = s>>5 (32): addr = ((P*32+c)*512) + frag_off.
__global__ __launch_bounds__(256) void prep_kernel(
    const float* __restrict__ x, const float* __restrict__ W1,
    const float* __restrict__ W2, float2* __restrict__ part,
    unsigned short* __restrict__ W1f, unsigned short* __restrict__ W2f) {
  const int blk = blockIdx.x;
  if (blk < 1024) {
    const int b = blk >> 4, c = blk & 15, t = threadIdx.x;
    const float4* xb = (const float4*)(x + (size_t)b * (S_ * D_) + c * 8192);
    float s = 0.f, q = 0.f;
#pragma unroll
    for (int i = 0; i < 8; ++i) {
      float4 v = xb[i * 256 + t];
      s += v.x + v.y + v.z + v.w;
      q += v.x * v.x + v.y * v.y + v.z * v.z + v.w * v.w;
    }
#pragma unroll
    for (int o = 32; o > 0; o >>= 1) {
      s += __shfl_down(s, o, 64);
      q += __shfl_down(q, o, 64);
    }
    __shared__ float2 w4[4];
    const int wave = t >> 6, lane = t & 63;
    if (lane == 0) w4[wave] = make_float2(s, q);
    __syncthreads();
    if (t == 0) {
      float ss = 0.f, qq = 0.f;
#pragma unroll
      for (int i = 0; i < 4; ++i) { ss += w4[i].x; qq += w4[i].y; }
      part[blk] = make_float2(ss, qq);
    }
  } else {
    const int id = (blk - 1024) * 256 + threadIdx.x;  // 0 .. 524287
    const int perW = (S_ * S_) / 4;
    const float* src = (id < perW) ? W1 : W2;
    unsigned short* dst = (id < perW) ? W1f : W2f;
    const int i4 = (id < perW) ? id : id - perW;
    const int flat = i4 * 4;
    const int trow = flat >> 10;       // t
    const int scol = flat & 1023;      // s (multiple of 4)
    float4 v = ((const float4*)src)[i4];
    ushort4 o;
    o.x = f2bf((scol + 0 <= trow) ? v.x : 0.f);
    o.y = f2bf((scol + 1 <= trow) ? v.y : 0.f);
    o.z = f2bf((scol + 2 <= trow) ? v.z : 0.f);
    o.w = f2bf((scol + 3 <= trow) ? v.w : 0.f);
    const size_t fa = ((size_t)(trow >> 4) * 32 + (scol >> 5)) * 512 +
                      ((scol >> 3) & 3) * 128 + (trow & 15) * 8 + (scol & 4);
    *(ushort4*)(dst + fa) = o;
  }
}

// ------- normalize + write hT in fragment-tiled layout (B-operand) ----------
// hTf[b]: panel p = d>>4 (8), chunk c = s>>5 (32): b*131072 + (p*32+c)*512.
__global__ __launch_bounds__(256) void norm_t_kernel(const float* __restrict__ x,
                                                     const float* __restrict__ w,
                                                     const float* __restrict__ bb,
                                                     const float2* __restrict__ part,
                                                     unsigned short* __restrict__ hTf) {
  __shared__ unsigned short lds[128 * 72];   // [d][s-tile 64 + 8 pad]
  const int blk = blockIdx.x;
  const int b = blk >> 4;
  const int s0 = (blk & 15) * 64;
  const int t = threadIdx.x;
  const int wave = t >> 6, lane = t & 63;
  const int quad = lane >> 4, l16 = lane & 15;
  float sum = 0.f, sumq = 0.f;
#pragma unroll
  for (int i = 0; i < 16; ++i) {
    float2 p = part[b * 16 + i];
    sum += p.x; sumq += p.y;
  }
  const float inv = 1.0f / (S_ * D_);
  const float mu = sum * inv;
  const float rs = rsqrtf(sumq * inv - mu * mu + 1e-5f);

  const float4* xb = (const float4*)(x + ((size_t)b * S_ + s0) * D_);
  const float4* wb = (const float4*)(w + (size_t)s0 * D_);
  const float4* bv4 = (const float4*)(bb + (size_t)s0 * D_);
#pragma unroll
  for (int r = 0; r < 8; ++r) {
    const int f = r * 256 + t;
    const int srow = f >> 5;
    const int c4 = f & 31;
    float4 xv = xb[f];
    float4 wv = wb[f];
    float4 bvv = bv4[f];
    float h0 = (xv.x - mu) * rs * wv.x + bvv.x;
    float h1 = (xv.y - mu) * rs * wv.y + bvv.y;
    float h2 = (xv.z - mu) * rs * wv.z + bvv.z;
    float h3 = (xv.w - mu) * rs * wv.w + bvv.w;
    const int d0 = c4 * 4;
    lds[(d0 + 0) * 72 + srow] = f2bf(h0);
    lds[(d0 + 1) * 72 + srow] = f2bf(h1);
    lds[(d0 + 2) * 72 + srow] = f2bf(h2);
    lds[(d0 + 3) * 72 + srow] = f2bf(h3);
  }
  __syncthreads();
  unsigned short* outp = hTf + (size_t)b * (D_ * S_);
  const int cg0 = (blk & 15) * 2;
#pragma unroll
  for (int ff = 0; ff < 4; ++ff) {
    const int f = wave * 4 + ff;       // 16 fragments per block
    const int p = f >> 1, cl = f & 1;
    const int d = p * 16 + l16;
    const int sb = cl * 32 + quad * 8;
    bf16x8 v = *(const bf16x8*)(lds + d * 72 + sb);
    *(bf16x8*)(outp + ((size_t)p * 32 + cg0 + cl) * 512 + lane * 8) = v;
  }
}

// ------------- causal batched GEMM, barrier-free, fragment-tiled -------------
// BM=64 (t), BN=128 (d); wave owns 64m x 32n. All operand loads are coalesced
// 1KB fragment loads (base + lane*16B). 2-deep prefetch, no __syncthreads in
// the K-loop. XCD-aware decode; mt = j<8 ? j : j^3 balances causal trips (34
// per CU). GEMM1 epilogue: hardswish -> LDS [d][t] -> fragment-tiled uTf.
// GEMM2 epilogue: residual add, fp32 direct to Out.
template <bool HSWISH>
__global__ __launch_bounds__(256, 4) void gemm_causal(
    const unsigned short* __restrict__ Af, const unsigned short* __restrict__ Bf,
    unsigned short* __restrict__ Uf, const float* __restrict__ Xres,
    float* __restrict__ Out) {
  const int t = threadIdx.x;
  const int wave = t >> 6, lane = t & 63;
  const int quad = lane >> 4, l16 = lane & 15;

  const int bi = blockIdx.x;
  const int xcd = bi & 7;
  const int slot = bi >> 3;            // 0..127
  const int b = xcd * 8 + (slot & 7);
  const int j = slot >> 3;             // 0..15
  const int mt = (j < 8) ? j : (j ^ 3);
  const int row0 = mt * 64;

  const unsigned short* pA = Af + ((size_t)mt * 4 * 32) * 512 + lane * 8;
  const unsigned short* pB = Bf + ((size_t)(b * 8 + wave * 2) * 32) * 512 + lane * 8;

  const int cend = 2 * (mt + 1);       // 32-wide k-chunks; even, >= 2

  f32x4 acc[4][2] = {};
  bf16x8 A0[4], A1[4], B0[2], B1[2];
#pragma unroll
  for (int i = 0; i < 4; ++i) {
    A0[i] = *(const bf16x8*)(pA + i * 16384);
    A1[i] = *(const bf16x8*)(pA + i * 16384 + 512);
  }
#pragma unroll
  for (int jj = 0; jj < 2; ++jj) {
    B0[jj] = *(const bf16x8*)(pB + jj * 16384);
    B1[jj] = *(const bf16x8*)(pB + jj * 16384 + 512);
  }

  for (int kt = 0; kt < cend; kt += 2) {
    bf16x8 An[4], Am[4], Bn[2], Bm[2];
    if (kt + 2 < cend) {
      const int o0 = (kt + 2) * 512, o1 = (kt + 3) * 512;
#pragma unroll
      for (int i = 0; i < 4; ++i) {
        An[i] = *(const bf16x8*)(pA + i * 16384 + o0);
        Am[i] = *(const bf16x8*)(pA + i * 16384 + o1);
      }
#pragma unroll
      for (int jj = 0; jj < 2; ++jj) {
        Bn[jj] = *(const bf16x8*)(pB + jj * 16384 + o0);
        Bm[jj] = *(const bf16x8*)(pB + jj * 16384 + o1);
      }
    }
#pragma unroll
    for (int i = 0; i < 4; ++i)
#pragma unroll
      for (int jj = 0; jj < 2; ++jj)
        acc[i][jj] = __builtin_amdgcn_mfma_f32_16x16x32_bf16(A0[i], B0[jj],
                                                             acc[i][jj], 0, 0, 0);
#pragma unroll
    for (int i = 0; i < 4; ++i)
#pragma unroll
      for (int jj = 0; jj < 2; ++jj)
        acc[i][jj] = __builtin_amdgcn_mfma_f32_16x16x32_bf16(A1[i], B1[jj],
                                                             acc[i][jj], 0, 0, 0);
#pragma unroll
    for (int i = 0; i < 4; ++i) { A0[i] = An[i]; A1[i] = Am[i]; }
#pragma unroll
    for (int jj = 0; jj < 2; ++jj) { B0[jj] = Bn[jj]; B1[jj] = Bm[jj]; }
  }

  if (HSWISH) {
    __shared__ __align__(16) unsigned short ldsT[128 * 72];  // [d][t 64 + pad]
#pragma unroll
    for (int i = 0; i < 4; ++i)
#pragma unroll
      for (int jj = 0; jj < 2; ++jj) {
        ushort4 pk;
        float v0 = acc[i][jj][0], v1 = acc[i][jj][1], v2 = acc[i][jj][2], v3 = acc[i][jj][3];
        pk.x = f2bf(v0 * fminf(fmaxf(v0 + 3.f, 0.f), 6.f) * (1.f / 6.f));
        pk.y = f2bf(v1 * fminf(fmaxf(v1 + 3.f, 0.f), 6.f) * (1.f / 6.f));
        pk.z = f2bf(v2 * fminf(fmaxf(v2 + 3.f, 0.f), 6.f) * (1.f / 6.f));
        pk.w = f2bf(v3 * fminf(fmaxf(v3 + 3.f, 0.f), 6.f) * (1.f / 6.f));
        const int n = wave * 32 + jj * 16 + l16;    // d
        const int m0 = i * 16 + quad * 4;           // t within 64-tile
        *(ushort4*)(ldsT + n * 72 + m0) = pk;
      }
    __syncthreads();
    unsigned short* gU = Uf + (size_t)b * (D_ * S_);
#pragma unroll
    for (int ff = 0; ff < 4; ++ff) {
      const int f = wave * 4 + ff;
      const int p = f >> 1, cl = f & 1;
      const int d = p * 16 + l16;
      const int tb = cl * 32 + quad * 8;
      bf16x8 v = *(const bf16x8*)(ldsT + d * 72 + tb);
      *(bf16x8*)(gU + ((size_t)p * 32 + mt * 2 + cl) * 512 + lane * 8) = v;
    }
  } else {
    float* gO = Out + (size_t)b * S_ * D_;
    const float* gX = Xres + (size_t)b * S_ * D_;
#pragma unroll
    for (int i = 0; i < 4; ++i) {
      const int mrow0 = row0 + i * 16 + quad * 4;
#pragma unroll
      for (int jj = 0; jj < 2; ++jj) {
        const int col = wave * 32 + jj * 16 + l16;
#pragma unroll
        for (int r = 0; r < 4; ++r) {
          const int addr = (mrow0 + r) * D_ + col;
          gO[addr] = gX[addr] + acc[i][jj][r];
        }
      }
    }
  }
}

extern "C" void kernel_launch(void* const* d_in, const int* in_sizes, int n_in,
                              void* d_out, int out_size, void* d_ws, size_t ws_size,
                              hipStream_t stream) {
  const float* x = (const float*)d_in[0];
  const float* ln_w = (const float*)d_in[1];
  const float* ln_b = (const float*)d_in[2];
  const float* W1 = (const float*)d_in[3];
  const float* W2 = (const float*)d_in[4];
  float* out = (float*)d_out;

  char* ws = (char*)d_ws;
  float2* part = (float2*)ws;                                // 8 KiB
  unsigned short* W1f = (unsigned short*)(ws + 16384);       // 2 MiB
  unsigned short* W2f = W1f + (size_t)S_ * S_;               // 2 MiB
  unsigned short* hTf = W2f + (size_t)S_ * S_;               // 16 MiB
  unsigned short* uTf = hTf + (size_t)NB * D_ * S_;          // 16 MiB

  prep_kernel<<<3072, 256, 0, stream>>>(x, W1, W2, part, W1f, W2f);
  norm_t_kernel<<<NB * 16, 256, 0, stream>>>(x, ln_w, ln_b, part, hTf);
  gemm_causal<true><<<1024, 256, 0, stream>>>(W1f, hTf, uTf, nullptr, nullptr);
  gemm_causal<false><<<1024, 256, 0, stream>>>(W2f, uTf, nullptr, x, out);
}

// Round 6
// 137.764 us; speedup vs baseline: 1.7165x; 1.3108x over previous
//
#include <hip/hip_runtime.h>
#include <hip/hip_bf16.h>

#define NB 64
#define S_ 1024
#define D_ 128

typedef __attribute__((ext_vector_type(8))) short bf16x8;
typedef __attribute__((ext_vector_type(4))) float f32x4;

// Fragment-tiled layout: operands stored as 16-row x 32-k panels of 1KB,
// element (r,k) at short-offset (((k>>3)&3)*16 + (r&15))*8 + (k&7) ==
// lane*8 + j in MFMA A/B fragment order -> a wave fragment load/store is
// base + lane*16B: one coalesced 1KB transaction.

__device__ __forceinline__ unsigned short f2bf(float f) {
  __hip_bfloat16 h = __float2bfloat16(f);
  return __builtin_bit_cast(unsigned short, h);
}

__device__ __forceinline__ void async_copy16(const void* g, void* l) {
  __builtin_amdgcn_global_load_lds(
      (const __attribute__((address_space(1))) unsigned int*)g,
      (__attribute__((address_space(3))) unsigned int*)l, 16, 0, 0);
}

// ---- fused: per-batch partial stats (blocks 0..1023) + W pack (1024..3071) --
__global__ __launch_bounds__(256) void prep_kernel(
    const float* __restrict__ x, const float* __restrict__ W1,
    const float* __restrict__ W2, float2* __restrict__ part,
    unsigned short* __restrict__ W1f, unsigned short* __restrict__ W2f) {
  const int blk = blockIdx.x;
  if (blk < 1024) {
    const int b = blk >> 4, c = blk & 15, t = threadIdx.x;
    const float4* xb = (const float4*)(x + (size_t)b * (S_ * D_) + c * 8192);
    float s = 0.f, q = 0.f;
#pragma unroll
    for (int i = 0; i < 8; ++i) {
      float4 v = xb[i * 256 + t];
      s += v.x + v.y + v.z + v.w;
      q += v.x * v.x + v.y * v.y + v.z * v.z + v.w * v.w;
    }
#pragma unroll
    for (int o = 32; o > 0; o >>= 1) {
      s += __shfl_down(s, o, 64);
      q += __shfl_down(q, o, 64);
    }
    __shared__ float2 w4[4];
    const int wave = t >> 6, lane = t & 63;
    if (lane == 0) w4[wave] = make_float2(s, q);
    __syncthreads();
    if (t == 0) {
      float ss = 0.f, qq = 0.f;
#pragma unroll
      for (int i = 0; i < 4; ++i) { ss += w4[i].x; qq += w4[i].y; }
      part[blk] = make_float2(ss, qq);
    }
  } else {
    const int id = (blk - 1024) * 256 + threadIdx.x;  // 0 .. 524287
    const int perW = (S_ * S_) / 4;
    const float* src = (id < perW) ? W1 : W2;
    unsigned short* dst = (id < perW) ? W1f : W2f;
    const int i4 = (id < perW) ? id : id - perW;
    const int flat = i4 * 4;
    const int trow = flat >> 10;       // t
    const int scol = flat & 1023;      // s (multiple of 4)
    float4 v = ((const float4*)src)[i4];
    ushort4 o;
    o.x = f2bf((scol + 0 <= trow) ? v.x : 0.f);
    o.y = f2bf((scol + 1 <= trow) ? v.y : 0.f);
    o.z = f2bf((scol + 2 <= trow) ? v.z : 0.f);
    o.w = f2bf((scol + 3 <= trow) ? v.w : 0.f);
    const size_t fa = ((size_t)(trow >> 4) * 32 + (scol >> 5)) * 512 +
                      ((scol >> 3) & 3) * 128 + (trow & 15) * 8 + (scol & 4);
    *(ushort4*)(dst + fa) = o;
  }
}

// ------- normalize + write hT in fragment-tiled layout (B-operand) ----------
__global__ __launch_bounds__(256) void norm_t_kernel(const float* __restrict__ x,
                                                     const float* __restrict__ w,
                                                     const float* __restrict__ bb,
                                                     const float2* __restrict__ part,
                                                     unsigned short* __restrict__ hTf) {
  __shared__ unsigned short lds[128 * 72];   // [d][s-tile 64 + 8 pad]
  const int blk = blockIdx.x;
  const int b = blk >> 4;
  const int s0 = (blk & 15) * 64;
  const int t = threadIdx.x;
  const int wave = t >> 6, lane = t & 63;
  const int quad = lane >> 4, l16 = lane & 15;
  float sum = 0.f, sumq = 0.f;
#pragma unroll
  for (int i = 0; i < 16; ++i) {
    float2 p = part[b * 16 + i];
    sum += p.x; sumq += p.y;
  }
  const float inv = 1.0f / (S_ * D_);
  const float mu = sum * inv;
  const float rs = rsqrtf(sumq * inv - mu * mu + 1e-5f);

  const float4* xb = (const float4*)(x + ((size_t)b * S_ + s0) * D_);
  const float4* wb = (const float4*)(w + (size_t)s0 * D_);
  const float4* bv4 = (const float4*)(bb + (size_t)s0 * D_);
#pragma unroll
  for (int r = 0; r < 8; ++r) {
    const int f = r * 256 + t;
    const int srow = f >> 5;
    const int c4 = f & 31;
    float4 xv = xb[f];
    float4 wv = wb[f];
    float4 bvv = bv4[f];
    float h0 = (xv.x - mu) * rs * wv.x + bvv.x;
    float h1 = (xv.y - mu) * rs * wv.y + bvv.y;
    float h2 = (xv.z - mu) * rs * wv.z + bvv.z;
    float h3 = (xv.w - mu) * rs * wv.w + bvv.w;
    const int d0 = c4 * 4;
    lds[(d0 + 0) * 72 + srow] = f2bf(h0);
    lds[(d0 + 1) * 72 + srow] = f2bf(h1);
    lds[(d0 + 2) * 72 + srow] = f2bf(h2);
    lds[(d0 + 3) * 72 + srow] = f2bf(h3);
  }
  __syncthreads();
  unsigned short* outp = hTf + (size_t)b * (D_ * S_);
  const int cg0 = (blk & 15) * 2;
#pragma unroll
  for (int ff = 0; ff < 4; ++ff) {
    const int f = wave * 4 + ff;       // 16 fragments per block
    const int p = f >> 1, cl = f & 1;
    const int d = p * 16 + l16;
    const int sb = cl * 32 + quad * 8;
    bf16x8 v = *(const bf16x8*)(lds + d * 72 + sb);
    *(bf16x8*)(outp + ((size_t)p * 32 + cg0 + cl) * 512 + lane * 8) = v;
  }
}

// ------------- causal batched GEMM: LDS-staged A, direct-prefetched B --------
// BM=64 (t), BN=128 (d); wave owns 64m x 32n. A (4x reused in block) is staged
// per 256-k panel into LDS (32KB verbatim copy of fragment-tiled panels) via
// global_load_lds, then read as ds_read_b128 fragments. B (no intra-block
// reuse) loads direct global->VGPR, coalesced 1KB, depth-4 rolling prefetch
// (Bp[c&3] reloaded with chunk g+4 right after use) so vmcnt stays
// fine-grained; barrier (vmcnt0 drain) only once per 8 chunks.
template <bool HSWISH>
__global__ __launch_bounds__(256, 4) void gemm_causal(
    const unsigned short* __restrict__ Af, const unsigned short* __restrict__ Bf,
    unsigned short* __restrict__ Uf, const float* __restrict__ Xres,
    float* __restrict__ Out) {
  __shared__ __align__(16) unsigned short ldsA[16384];   // 32 KB

  const int t = threadIdx.x;
  const int wave = t >> 6, lane = t & 63;
  const int quad = lane >> 4, l16 = lane & 15;

  const int bi = blockIdx.x;
  const int xcd = bi & 7;
  const int slot = bi >> 3;            // 0..127
  const int b = xcd * 8 + (slot & 7);
  const int j = slot >> 3;             // 0..15
  const int mt = (j < 8) ? j : (j ^ 3);
  const int row0 = mt * 64;

  const int cend = 2 * (mt + 1);       // active 32-k chunks (even, 2..32)
  const int npan = (cend + 7) >> 3;    // 256-k panels

  const unsigned short* Ab = Af + (size_t)mt * 4 * 32 * 512;
  const unsigned short* Bb = Bf + (size_t)b * (D_ * S_);

  f32x4 acc[4][2] = {};
  bf16x8 Bp[4][2];
#pragma unroll
  for (int g = 0; g < 4; ++g) {
    const int gg = (g < cend) ? g : 0;
#pragma unroll
    for (int jj = 0; jj < 2; ++jj)
      Bp[g][jj] = *(const bf16x8*)(Bb + ((size_t)(wave * 2 + jj) * 32 + gg) * 512 + lane * 8);
  }

  for (int p = 0; p < npan; ++p) {
    if (p) __syncthreads();            // protect LDS from prior-panel readers
#pragma unroll
    for (int jc = 0; jc < 8; ++jc) {   // stage 32KB: A panels [mt*4+iw][p*8+cc]
      const int flat16 = jc * 256 + t; // 16B units
      const int iw = flat16 >> 9;
      const int cc = (flat16 >> 6) & 7;
      const int li = flat16 & 63;
      async_copy16(Ab + ((size_t)iw * 32 + p * 8 + cc) * 512 + li * 8,
                   ldsA + flat16 * 8);
    }
    __syncthreads();                   // drains vmcnt; A panel ready
#pragma unroll
    for (int c = 0; c < 8; ++c) {
      const int g = p * 8 + c;
      if (g < cend) {
        bf16x8 af[4];
#pragma unroll
        for (int i = 0; i < 4; ++i)
          af[i] = *(const bf16x8*)(ldsA + i * 4096 + c * 512 + lane * 8);
#pragma unroll
        for (int i = 0; i < 4; ++i)
#pragma unroll
          for (int jj = 0; jj < 2; ++jj)
            acc[i][jj] = __builtin_amdgcn_mfma_f32_16x16x32_bf16(
                af[i], Bp[c & 3][jj], acc[i][jj], 0, 0, 0);
        const int gn = (g + 4 < cend) ? (g + 4) : 0;
#pragma unroll
        for (int jj = 0; jj < 2; ++jj)
          Bp[c & 3][jj] = *(const bf16x8*)(
              Bb + ((size_t)(wave * 2 + jj) * 32 + gn) * 512 + lane * 8);
      }
    }
  }

  if (HSWISH) {
    __syncthreads();                   // done reading ldsA; reuse for transpose
    unsigned short* ldsT = ldsA;       // [d][t 64 + 8 pad] = 18KB of 32KB
#pragma unroll
    for (int i = 0; i < 4; ++i)
#pragma unroll
      for (int jj = 0; jj < 2; ++jj) {
        ushort4 pk;
        float v0 = acc[i][jj][0], v1 = acc[i][jj][1], v2 = acc[i][jj][2], v3 = acc[i][jj][3];
        pk.x = f2bf(v0 * fminf(fmaxf(v0 + 3.f, 0.f), 6.f) * (1.f / 6.f));
        pk.y = f2bf(v1 * fminf(fmaxf(v1 + 3.f, 0.f), 6.f) * (1.f / 6.f));
        pk.z = f2bf(v2 * fminf(fmaxf(v2 + 3.f, 0.f), 6.f) * (1.f / 6.f));
        pk.w = f2bf(v3 * fminf(fmaxf(v3 + 3.f, 0.f), 6.f) * (1.f / 6.f));
        const int n = wave * 32 + jj * 16 + l16;    // d
        const int m0 = i * 16 + quad * 4;           // t within 64-tile
        *(ushort4*)(ldsT + n * 72 + m0) = pk;
      }
    __syncthreads();
    unsigned short* gU = Uf + (size_t)b * (D_ * S_);
#pragma unroll
    for (int ff = 0; ff < 4; ++ff) {
      const int f = wave * 4 + ff;
      const int p2 = f >> 1, cl = f & 1;
      const int d = p2 * 16 + l16;
      const int tb = cl * 32 + quad * 8;
      bf16x8 v = *(const bf16x8*)(ldsT + d * 72 + tb);
      *(bf16x8*)(gU + ((size_t)p2 * 32 + mt * 2 + cl) * 512 + lane * 8) = v;
    }
  } else {
    float* gO = Out + (size_t)b * S_ * D_;
    const float* gX = Xres + (size_t)b * S_ * D_;
#pragma unroll
    for (int i = 0; i < 4; ++i) {
      const int mrow0 = row0 + i * 16 + quad * 4;
#pragma unroll
      for (int jj = 0; jj < 2; ++jj) {
        const int col = wave * 32 + jj * 16 + l16;
#pragma unroll
        for (int r = 0; r < 4; ++r) {
          const int addr = (mrow0 + r) * D_ + col;
          gO[addr] = gX[addr] + acc[i][jj][r];
        }
      }
    }
  }
}

extern "C" void kernel_launch(void* const* d_in, const int* in_sizes, int n_in,
                              void* d_out, int out_size, void* d_ws, size_t ws_size,
                              hipStream_t stream) {
  const float* x = (const float*)d_in[0];
  const float* ln_w = (const float*)d_in[1];
  const float* ln_b = (const float*)d_in[2];
  const float* W1 = (const float*)d_in[3];
  const float* W2 = (const float*)d_in[4];
  float* out = (float*)d_out;

  char* ws = (char*)d_ws;
  float2* part = (float2*)ws;                                // 8 KiB
  unsigned short* W1f = (unsigned short*)(ws + 16384);       // 2 MiB
  unsigned short* W2f = W1f + (size_t)S_ * S_;               // 2 MiB
  unsigned short* hTf = W2f + (size_t)S_ * S_;               // 16 MiB
  unsigned short* uTf = hTf + (size_t)NB * D_ * S_;          // 16 MiB

  prep_kernel<<<3072, 256, 0, stream>>>(x, W1, W2, part, W1f, W2f);
  norm_t_kernel<<<NB * 16, 256, 0, stream>>>(x, ln_w, ln_b, part, hTf);
  gemm_causal<true><<<1024, 256, 0, stream>>>(W1f, hTf, uTf, nullptr, nullptr);
  gemm_causal<false><<<1024, 256, 0, stream>>>(W2f, uTf, nullptr, x, out);
}